// Round 19
// baseline (366.025 us; speedup 1.0000x reference)
//
#include <hip/hip_runtime.h>

// TwoLayerSNN forward: B=256, T=1000, D=32, H=200, O=2
// Round 19 = round 18 (2 redundant blocks/batch, halved stores, VGPR<=64)
// with SC 20->8 so LDS drops 47.6KB -> ~24.5KB per block. Hypothesis: the
// effective LDS pairing pool is 64KB (r17 VGPR=68 and r18 VGPR=56 both
// failed to co-schedule at 46.5KB LDS; wave slots and threads fit), so
// 2 x 24.5KB < 64KB should finally allow 2 blocks/CU. SC=8 vs 20 was
// perf-neutral (r13 187 vs r14 184). All arithmetic bit-identical to r18.

constexpr int TB = 256;
constexpr int TT = 1000;
constexpr int DD = 32;
constexpr int HH = 200;
constexpr int OO = 2;
constexpr int CH = 40;                    // timesteps per x staging chunk (5 KB)
constexpr int NCH = TT / CH;              // 25
constexpr int SC = 8;                     // timesteps per barrier interval
constexpr int NSC = TT / SC;              // 125
constexpr int XF4 = CH * DD / 4;          // 320 float4 per chunk

typedef float v2f __attribute__((ext_vector_type(2)));

__device__ __forceinline__ v2f pk_fma(v2f a, v2f b, v2f c) {
#if __has_builtin(__builtin_elementwise_fma)
    return __builtin_elementwise_fma(a, b, c);
#else
    v2f r; r.x = fmaf(a.x, b.x, c.x); r.y = fmaf(a.y, b.y, c.y); return r;
#endif
}

template <int CTRL>
__device__ __forceinline__ float dpp_add(float v) {
    int t = __builtin_amdgcn_update_dpp(0, __float_as_int(v), CTRL, 0xf, 0xf, true);
    return v + __int_as_float(t);
}

__device__ __forceinline__ float read_lane_f(float v, int l) {
    return __int_as_float(__builtin_amdgcn_readlane(__float_as_int(v), l));
}

__device__ __forceinline__ void block_sync_lds() {
    // Order LDS only (validated r8-r18): drain lgkm, raw barrier.
    asm volatile("s_waitcnt lgkmcnt(0)" ::: "memory");
    __builtin_amdgcn_s_barrier();
    asm volatile("" ::: "memory");
}

__global__ __launch_bounds__(576, 8)
void snn_fwd(const float* __restrict__ x,
             const float* __restrict__ w1,
             const float* __restrict__ w2,
             float* __restrict__ out)
{
    const int b    = blockIdx.x >> 1;
    const int half = blockIdx.x & 1;           // which h-half this block STORES
    const int tid  = threadIdx.x;
    const int lane = tid & 63;
    const int wid  = tid >> 6;
    const bool is_cons = (wid < 4);             // waves 0-3: consumers
    const bool is_prod = (wid >= 4 && wid < 8); // waves 4-7: producers
    const int ptid = tid - 256;                 // producer-local 0..255
    const bool act = is_cons && (tid < HH);
    // store predicate: this block stores h in [half*100, half*100+100)
    const bool act_st = act && (tid >= half * 100) && (tid < half * 100 + 100);
    const bool st_l2  = (half == 0);

    float* __restrict__ outp = out;                        // [TB][OO]
    float* __restrict__ s1o  = out + (size_t)TB * OO;      // [TB][TT][HH]
    float* __restrict__ m1o  = s1o + (size_t)TB * TT * HH; // [TB][TT][HH]
    float* __restrict__ s2o  = m1o + (size_t)TB * TT * HH; // [TB][TT][OO]
    float* __restrict__ m2o  = s2o + (size_t)TB * TT * OO; // [TB][TT][OO]

    const float A_SYN1 = (float)0.8187307530779818;
    const float IN_SC1 = (float)((1.0 - 0.8187307530779818) * 5.0);
    const float A_MEM1 = (float)0.9048374180359595;
    const float B_MEM1 = (float)(1.0 - 0.9048374180359595);
    const float TH1    = 0.5f;
    const float A_SYN2 = (float)0.9048374180359595;
    const float IN_SC2 = (float)((1.0 - 0.9048374180359595) * 10.0);
    const float A_MEM2 = (float)0.9512294245007140;
    const float B_MEM2 = (float)(1.0 - 0.9512294245007140);
    const float TH2    = 1.0f;

    __shared__ float4 xls[2][XF4];                    // 2 x 5 KB
    __shared__ float  dotb[2][SC][HH];                // 2 x 6.4 KB
    __shared__ __align__(16) float2 partv[2][SC][16]; // 2 x 1 KB

    const float* __restrict__ xb = x + (size_t)b * TT * DD;

    // producer: 50 hidden units per wave; w1 column as 16 float2 pairs
    const int ph   = (wid - 4) * 50 + lane;          // producer h
    const bool pact = is_prod && (lane < 50);
    v2f w1e[DD / 4], w1o[DD / 4];
#pragma unroll
    for (int i = 0; i < DD / 4; ++i) {
        w1e[i] = pact ? v2f{w1[(4 * i) * HH + ph],     w1[(4 * i + 1) * HH + ph]} : v2f{0.f, 0.f};
        w1o[i] = pact ? v2f{w1[(4 * i + 2) * HH + ph], w1[(4 * i + 3) * HH + ph]} : v2f{0.f, 0.f};
    }
    // consumer: w2 row
    const float w2x = act ? w2[tid * OO + 0] : 0.0f;
    const float w2y = act ? w2[tid * OO + 1] : 0.0f;

    // stage chunk 0 (5 KB, 320 float4) using consumer threads (one-time)
    if (is_cons) {
        const float4* g = (const float4*)xb;
        if (2 * tid     < XF4) xls[0][2 * tid]     = g[2 * tid];
        if (2 * tid + 1 < XF4) xls[0][2 * tid + 1] = g[2 * tid + 1];
    }
    block_sync_lds();

    // produce(j): dots for sub-chunk j into dotb[j&1]. Same fma order as
    // r14-r18 (bit-identical); x processed in two 4-float4 groups to keep
    // live X registers at 16 (VGPR budget).
    auto produce = [&](int j) {
        const int tj = j * SC;
        const float4* xq = &xls[(tj / CH) & 1][(tj % CH) * (DD / 4)];
#pragma unroll
        for (int s = 0; s < SC; ++s) {
            v2f A01 = {0.f, 0.f}, A23 = {0.f, 0.f};
            {
                const float4 X0 = xq[s * 8 + 0], X1 = xq[s * 8 + 1];
                const float4 X2 = xq[s * 8 + 2], X3 = xq[s * 8 + 3];
                A01 = pk_fma(v2f{X0.x, X0.y}, w1e[0], A01);
                A23 = pk_fma(v2f{X0.z, X0.w}, w1o[0], A23);
                A01 = pk_fma(v2f{X1.x, X1.y}, w1e[1], A01);
                A23 = pk_fma(v2f{X1.z, X1.w}, w1o[1], A23);
                A01 = pk_fma(v2f{X2.x, X2.y}, w1e[2], A01);
                A23 = pk_fma(v2f{X2.z, X2.w}, w1o[2], A23);
                A01 = pk_fma(v2f{X3.x, X3.y}, w1e[3], A01);
                A23 = pk_fma(v2f{X3.z, X3.w}, w1o[3], A23);
            }
            {
                const float4 X4 = xq[s * 8 + 4], X5 = xq[s * 8 + 5];
                const float4 X6 = xq[s * 8 + 6], X7 = xq[s * 8 + 7];
                A01 = pk_fma(v2f{X4.x, X4.y}, w1e[4], A01);
                A23 = pk_fma(v2f{X4.z, X4.w}, w1o[4], A23);
                A01 = pk_fma(v2f{X5.x, X5.y}, w1e[5], A01);
                A23 = pk_fma(v2f{X5.z, X5.w}, w1o[5], A23);
                A01 = pk_fma(v2f{X6.x, X6.y}, w1e[6], A01);
                A23 = pk_fma(v2f{X6.z, X6.w}, w1o[6], A23);
                A01 = pk_fma(v2f{X7.x, X7.y}, w1e[7], A01);
                A23 = pk_fma(v2f{X7.z, X7.w}, w1o[7], A23);
            }
            const float dotv = __fadd_rn(__fadd_rn(A01.x, A01.y),
                                         __fadd_rn(A23.x, A23.y));
            if (pact) dotb[j & 1][s][ph] = dotv;
        }
    };

    // prologue: fill dotb[0] for sub-chunk 0
    if (is_prod) produce(0);
    block_sync_lds();

    float syn1 = 0.0f, mem1 = 0.0f;
    double accx = 0.0, accy = 0.0;
    v2f syn2 = {0.f, 0.f}, mem2 = {0.f, 0.f};
    const v2f A2v  = {A_SYN2, A_SYN2};
    const v2f SC2v = {IN_SC2, IN_SC2};
    const v2f AM2v = {A_MEM2, A_MEM2};
    const v2f BM2v = {B_MEM2, B_MEM2};
    const v2f TH2v = {TH2, TH2};

    float* __restrict__ s1p = s1o + (size_t)b * TT * HH + tid;
    float* __restrict__ m1p = m1o + (size_t)b * TT * HH + tid;
    float2* __restrict__ s2p = (float2*)(s2o + (size_t)b * TT * OO);
    float2* __restrict__ m2p = (float2*)(m2o + (size_t)b * TT * OO);

    // layer-2 for sub-chunk j (wave 8 only): lane-parallel merge of the 16
    // row-partials (4 steps per pass, 2 passes), then the pk-packed serial
    // chain (per-component roundings identical to scalar __f*_rn; r14-r18).
    auto l2_chunk = [&](int j) {
#pragma clang fp contract(off)
        const int g = lane >> 4;     // step within pass (0..3)
        const int p = lane & 15;     // partial index
#pragma unroll
        for (int hf = 0; hf < SC / 4; ++hf) {
            const float2 v = partv[j & 1][4 * hf + g][p];
            float cxv = v.x, cyv = v.y;
            cxv = dpp_add<0x111>(cxv); cyv = dpp_add<0x111>(cyv);
            cxv = dpp_add<0x112>(cxv); cyv = dpp_add<0x112>(cyv);
            cxv = dpp_add<0x114>(cxv); cyv = dpp_add<0x114>(cyv);
            cxv = dpp_add<0x118>(cxv); cyv = dpp_add<0x118>(cyv);
            // merged sums at lanes 15/31/47/63 for steps 4*hf+0..3
#pragma unroll
            for (int gg = 0; gg < 4; ++gg) {
                const v2f d = {read_lane_f(cxv, 16 * gg + 15),
                               read_lane_f(cyv, 16 * gg + 15)};
                syn2 = (A2v * syn2) + (SC2v * d);
                mem2 = (AM2v * mem2) + (BM2v * syn2);
                const float s2x = (mem2.x - TH2 > 0.0f) ? 1.0f : 0.0f;
                const float s2y = (mem2.y - TH2 > 0.0f) ? 1.0f : 0.0f;
                const v2f s2v = {s2x, s2y};
                mem2 = mem2 - (s2v * TH2v);
                const int t = j * SC + 4 * hf + gg;
                if (tid == 512 && st_l2) {
                    s2p[t] = make_float2(s2x, s2y);
                    m2p[t] = make_float2(mem2.x, mem2.y);
                }
                if (t > 0) { accx += (double)mem2.x; accy += (double)mem2.y; }
            }
        }
    };

    for (int sc = 0; sc < NSC; ++sc) {
        const int t0   = sc * SC;
        const int c    = t0 / CH;
        const int cpos = t0 % CH;

        if (is_cons) {
            // ---- consumer: this sub-chunk's dots from LDS ----
            float D[SC];
#pragma unroll
            for (int s = 0; s < SC; ++s) D[s] = dotb[sc & 1][s][tid];

            // ---- 8 steps: recurrence + (half) stores + 4-level DPP ----
#pragma unroll
            for (int s = 0; s < SC; ++s) {
                const float dot = D[s];
                syn1 = __fadd_rn(__fmul_rn(A_SYN1, syn1), __fmul_rn(IN_SC1, dot));
                mem1 = __fadd_rn(__fmul_rn(A_MEM1, mem1), __fmul_rn(B_MEM1, syn1));
                const float s1v = (mem1 - TH1 > 0.0f) ? 1.0f : 0.0f;
                mem1 = __fsub_rn(mem1, __fmul_rn(s1v, TH1));

                if (act_st) {
                    s1p[(size_t)(t0 + s) * HH] = s1v;
                    m1p[(size_t)(t0 + s) * HH] = mem1;
                }

                float cx = s1v * w2x;
                float cy = s1v * w2y;
                cx = dpp_add<0x111>(cx); cy = dpp_add<0x111>(cy);
                cx = dpp_add<0x112>(cx); cy = dpp_add<0x112>(cy);
                cx = dpp_add<0x114>(cx); cy = dpp_add<0x114>(cy);
                cx = dpp_add<0x118>(cx); cy = dpp_add<0x118>(cy);
                // row sums at lanes 15/31/47/63 -> 4 partials per wave
                if ((lane & 15) == 15)
                    partv[sc & 1][s][wid * 4 + (lane >> 4)] = make_float2(cx, cy);
            }
        } else if (is_prod) {
            // ---- producer: stage next chunk (same-iteration load/commit,
            //      4 barriers before first read); dots for sub-chunk sc+1 ----
            float4 pr0, pr1;
            const bool stage = (cpos == 0 && c + 1 < NCH);
            if (stage) {
                const float4* g = (const float4*)(xb + (size_t)(c + 1) * CH * DD);
                if (2 * ptid     < XF4) pr0 = g[2 * ptid];
                if (2 * ptid + 1 < XF4) pr1 = g[2 * ptid + 1];
            }

            if (sc + 1 < NSC) produce(sc + 1);

            if (stage) {
                if (2 * ptid     < XF4) xls[(c + 1) & 1][2 * ptid]     = pr0;
                if (2 * ptid + 1 < XF4) xls[(c + 1) & 1][2 * ptid + 1] = pr1;
            }
        } else {
            // ---- wave 8: layer-2 for the previous sub-chunk ----
            if (sc > 0) l2_chunk(sc - 1);
        }

        block_sync_lds();
    }

    // epilogue: layer-2 for the final sub-chunk (wave 8)
    if (wid == 8) {
        l2_chunk(NSC - 1);
        if (tid == 512 && st_l2) {
            outp[b * OO + 0] = (float)accx / 1000.0f;
            outp[b * OO + 1] = (float)accy / 1000.0f;
        }
    }
}

extern "C" void kernel_launch(void* const* d_in, const int* in_sizes, int n_in,
                              void* d_out, int out_size, void* d_ws, size_t ws_size,
                              hipStream_t stream) {
    const float* x  = (const float*)d_in[0];   // [256,1000,32]
    const float* w1 = (const float*)d_in[1];   // [32,200]
    const float* w2 = (const float*)d_in[2];   // [200,2]
    float* out = (float*)d_out;

    dim3 grid(2 * TB), block(576);
    hipLaunchKernelGGL(snn_fwd, grid, block, 0, stream, x, w1, w2, out);
}

// Round 20
// 365.463 us; speedup vs baseline: 1.0015x; 1.0015x over previous
//
#include <hip/hip_runtime.h>

// TwoLayerSNN forward: B=256, T=1000, D=32, H=200, O=2
// Round 19 = round 18 (2 redundant blocks/batch, halved stores, VGPR<=64)
// with SC 20->8 so LDS drops 47.6KB -> ~24.5KB per block. Hypothesis: the
// effective LDS pairing pool is 64KB (r17 VGPR=68 and r18 VGPR=56 both
// failed to co-schedule at 46.5KB LDS; wave slots and threads fit), so
// 2 x 24.5KB < 64KB should finally allow 2 blocks/CU. SC=8 vs 20 was
// perf-neutral (r13 187 vs r14 184). All arithmetic bit-identical to r18.

constexpr int TB = 256;
constexpr int TT = 1000;
constexpr int DD = 32;
constexpr int HH = 200;
constexpr int OO = 2;
constexpr int CH = 40;                    // timesteps per x staging chunk (5 KB)
constexpr int NCH = TT / CH;              // 25
constexpr int SC = 8;                     // timesteps per barrier interval
constexpr int NSC = TT / SC;              // 125
constexpr int XF4 = CH * DD / 4;          // 320 float4 per chunk

typedef float v2f __attribute__((ext_vector_type(2)));

__device__ __forceinline__ v2f pk_fma(v2f a, v2f b, v2f c) {
#if __has_builtin(__builtin_elementwise_fma)
    return __builtin_elementwise_fma(a, b, c);
#else
    v2f r; r.x = fmaf(a.x, b.x, c.x); r.y = fmaf(a.y, b.y, c.y); return r;
#endif
}

template <int CTRL>
__device__ __forceinline__ float dpp_add(float v) {
    int t = __builtin_amdgcn_update_dpp(0, __float_as_int(v), CTRL, 0xf, 0xf, true);
    return v + __int_as_float(t);
}

__device__ __forceinline__ float read_lane_f(float v, int l) {
    return __int_as_float(__builtin_amdgcn_readlane(__float_as_int(v), l));
}

__device__ __forceinline__ void block_sync_lds() {
    // Order LDS only (validated r8-r18): drain lgkm, raw barrier.
    asm volatile("s_waitcnt lgkmcnt(0)" ::: "memory");
    __builtin_amdgcn_s_barrier();
    asm volatile("" ::: "memory");
}

__global__ __launch_bounds__(576, 8)
void snn_fwd(const float* __restrict__ x,
             const float* __restrict__ w1,
             const float* __restrict__ w2,
             float* __restrict__ out)
{
    const int b    = blockIdx.x >> 1;
    const int half = blockIdx.x & 1;           // which h-half this block STORES
    const int tid  = threadIdx.x;
    const int lane = tid & 63;
    const int wid  = tid >> 6;
    const bool is_cons = (wid < 4);             // waves 0-3: consumers
    const bool is_prod = (wid >= 4 && wid < 8); // waves 4-7: producers
    const int ptid = tid - 256;                 // producer-local 0..255
    const bool act = is_cons && (tid < HH);
    // store predicate: this block stores h in [half*100, half*100+100)
    const bool act_st = act && (tid >= half * 100) && (tid < half * 100 + 100);
    const bool st_l2  = (half == 0);

    float* __restrict__ outp = out;                        // [TB][OO]
    float* __restrict__ s1o  = out + (size_t)TB * OO;      // [TB][TT][HH]
    float* __restrict__ m1o  = s1o + (size_t)TB * TT * HH; // [TB][TT][HH]
    float* __restrict__ s2o  = m1o + (size_t)TB * TT * HH; // [TB][TT][OO]
    float* __restrict__ m2o  = s2o + (size_t)TB * TT * OO; // [TB][TT][OO]

    const float A_SYN1 = (float)0.8187307530779818;
    const float IN_SC1 = (float)((1.0 - 0.8187307530779818) * 5.0);
    const float A_MEM1 = (float)0.9048374180359595;
    const float B_MEM1 = (float)(1.0 - 0.9048374180359595);
    const float TH1    = 0.5f;
    const float A_SYN2 = (float)0.9048374180359595;
    const float IN_SC2 = (float)((1.0 - 0.9048374180359595) * 10.0);
    const float A_MEM2 = (float)0.9512294245007140;
    const float B_MEM2 = (float)(1.0 - 0.9512294245007140);
    const float TH2    = 1.0f;

    __shared__ float4 xls[2][XF4];                    // 2 x 5 KB
    __shared__ float  dotb[2][SC][HH];                // 2 x 6.4 KB
    __shared__ __align__(16) float2 partv[2][SC][16]; // 2 x 1 KB

    const float* __restrict__ xb = x + (size_t)b * TT * DD;

    // producer: 50 hidden units per wave; w1 column as 16 float2 pairs
    const int ph   = (wid - 4) * 50 + lane;          // producer h
    const bool pact = is_prod && (lane < 50);
    v2f w1e[DD / 4], w1o[DD / 4];
#pragma unroll
    for (int i = 0; i < DD / 4; ++i) {
        w1e[i] = pact ? v2f{w1[(4 * i) * HH + ph],     w1[(4 * i + 1) * HH + ph]} : v2f{0.f, 0.f};
        w1o[i] = pact ? v2f{w1[(4 * i + 2) * HH + ph], w1[(4 * i + 3) * HH + ph]} : v2f{0.f, 0.f};
    }
    // consumer: w2 row
    const float w2x = act ? w2[tid * OO + 0] : 0.0f;
    const float w2y = act ? w2[tid * OO + 1] : 0.0f;

    // stage chunk 0 (5 KB, 320 float4) using consumer threads (one-time)
    if (is_cons) {
        const float4* g = (const float4*)xb;
        if (2 * tid     < XF4) xls[0][2 * tid]     = g[2 * tid];
        if (2 * tid + 1 < XF4) xls[0][2 * tid + 1] = g[2 * tid + 1];
    }
    block_sync_lds();

    // produce(j): dots for sub-chunk j into dotb[j&1]. Same fma order as
    // r14-r18 (bit-identical); x processed in two 4-float4 groups to keep
    // live X registers at 16 (VGPR budget).
    auto produce = [&](int j) {
        const int tj = j * SC;
        const float4* xq = &xls[(tj / CH) & 1][(tj % CH) * (DD / 4)];
#pragma unroll
        for (int s = 0; s < SC; ++s) {
            v2f A01 = {0.f, 0.f}, A23 = {0.f, 0.f};
            {
                const float4 X0 = xq[s * 8 + 0], X1 = xq[s * 8 + 1];
                const float4 X2 = xq[s * 8 + 2], X3 = xq[s * 8 + 3];
                A01 = pk_fma(v2f{X0.x, X0.y}, w1e[0], A01);
                A23 = pk_fma(v2f{X0.z, X0.w}, w1o[0], A23);
                A01 = pk_fma(v2f{X1.x, X1.y}, w1e[1], A01);
                A23 = pk_fma(v2f{X1.z, X1.w}, w1o[1], A23);
                A01 = pk_fma(v2f{X2.x, X2.y}, w1e[2], A01);
                A23 = pk_fma(v2f{X2.z, X2.w}, w1o[2], A23);
                A01 = pk_fma(v2f{X3.x, X3.y}, w1e[3], A01);
                A23 = pk_fma(v2f{X3.z, X3.w}, w1o[3], A23);
            }
            {
                const float4 X4 = xq[s * 8 + 4], X5 = xq[s * 8 + 5];
                const float4 X6 = xq[s * 8 + 6], X7 = xq[s * 8 + 7];
                A01 = pk_fma(v2f{X4.x, X4.y}, w1e[4], A01);
                A23 = pk_fma(v2f{X4.z, X4.w}, w1o[4], A23);
                A01 = pk_fma(v2f{X5.x, X5.y}, w1e[5], A01);
                A23 = pk_fma(v2f{X5.z, X5.w}, w1o[5], A23);
                A01 = pk_fma(v2f{X6.x, X6.y}, w1e[6], A01);
                A23 = pk_fma(v2f{X6.z, X6.w}, w1o[6], A23);
                A01 = pk_fma(v2f{X7.x, X7.y}, w1e[7], A01);
                A23 = pk_fma(v2f{X7.z, X7.w}, w1o[7], A23);
            }
            const float dotv = __fadd_rn(__fadd_rn(A01.x, A01.y),
                                         __fadd_rn(A23.x, A23.y));
            if (pact) dotb[j & 1][s][ph] = dotv;
        }
    };

    // prologue: fill dotb[0] for sub-chunk 0
    if (is_prod) produce(0);
    block_sync_lds();

    float syn1 = 0.0f, mem1 = 0.0f;
    double accx = 0.0, accy = 0.0;
    v2f syn2 = {0.f, 0.f}, mem2 = {0.f, 0.f};
    const v2f A2v  = {A_SYN2, A_SYN2};
    const v2f SC2v = {IN_SC2, IN_SC2};
    const v2f AM2v = {A_MEM2, A_MEM2};
    const v2f BM2v = {B_MEM2, B_MEM2};
    const v2f TH2v = {TH2, TH2};

    float* __restrict__ s1p = s1o + (size_t)b * TT * HH + tid;
    float* __restrict__ m1p = m1o + (size_t)b * TT * HH + tid;
    float2* __restrict__ s2p = (float2*)(s2o + (size_t)b * TT * OO);
    float2* __restrict__ m2p = (float2*)(m2o + (size_t)b * TT * OO);

    // layer-2 for sub-chunk j (wave 8 only): lane-parallel merge of the 16
    // row-partials (4 steps per pass, 2 passes), then the pk-packed serial
    // chain (per-component roundings identical to scalar __f*_rn; r14-r18).
    auto l2_chunk = [&](int j) {
#pragma clang fp contract(off)
        const int g = lane >> 4;     // step within pass (0..3)
        const int p = lane & 15;     // partial index
#pragma unroll
        for (int hf = 0; hf < SC / 4; ++hf) {
            const float2 v = partv[j & 1][4 * hf + g][p];
            float cxv = v.x, cyv = v.y;
            cxv = dpp_add<0x111>(cxv); cyv = dpp_add<0x111>(cyv);
            cxv = dpp_add<0x112>(cxv); cyv = dpp_add<0x112>(cyv);
            cxv = dpp_add<0x114>(cxv); cyv = dpp_add<0x114>(cyv);
            cxv = dpp_add<0x118>(cxv); cyv = dpp_add<0x118>(cyv);
            // merged sums at lanes 15/31/47/63 for steps 4*hf+0..3
#pragma unroll
            for (int gg = 0; gg < 4; ++gg) {
                const v2f d = {read_lane_f(cxv, 16 * gg + 15),
                               read_lane_f(cyv, 16 * gg + 15)};
                syn2 = (A2v * syn2) + (SC2v * d);
                mem2 = (AM2v * mem2) + (BM2v * syn2);
                const float s2x = (mem2.x - TH2 > 0.0f) ? 1.0f : 0.0f;
                const float s2y = (mem2.y - TH2 > 0.0f) ? 1.0f : 0.0f;
                const v2f s2v = {s2x, s2y};
                mem2 = mem2 - (s2v * TH2v);
                const int t = j * SC + 4 * hf + gg;
                if (tid == 512 && st_l2) {
                    s2p[t] = make_float2(s2x, s2y);
                    m2p[t] = make_float2(mem2.x, mem2.y);
                }
                if (t > 0) { accx += (double)mem2.x; accy += (double)mem2.y; }
            }
        }
    };

    for (int sc = 0; sc < NSC; ++sc) {
        const int t0   = sc * SC;
        const int c    = t0 / CH;
        const int cpos = t0 % CH;

        if (is_cons) {
            // ---- consumer: this sub-chunk's dots from LDS ----
            float D[SC];
#pragma unroll
            for (int s = 0; s < SC; ++s) D[s] = dotb[sc & 1][s][tid];

            // ---- 8 steps: recurrence + (half) stores + 4-level DPP ----
#pragma unroll
            for (int s = 0; s < SC; ++s) {
                const float dot = D[s];
                syn1 = __fadd_rn(__fmul_rn(A_SYN1, syn1), __fmul_rn(IN_SC1, dot));
                mem1 = __fadd_rn(__fmul_rn(A_MEM1, mem1), __fmul_rn(B_MEM1, syn1));
                const float s1v = (mem1 - TH1 > 0.0f) ? 1.0f : 0.0f;
                mem1 = __fsub_rn(mem1, __fmul_rn(s1v, TH1));

                if (act_st) {
                    s1p[(size_t)(t0 + s) * HH] = s1v;
                    m1p[(size_t)(t0 + s) * HH] = mem1;
                }

                float cx = s1v * w2x;
                float cy = s1v * w2y;
                cx = dpp_add<0x111>(cx); cy = dpp_add<0x111>(cy);
                cx = dpp_add<0x112>(cx); cy = dpp_add<0x112>(cy);
                cx = dpp_add<0x114>(cx); cy = dpp_add<0x114>(cy);
                cx = dpp_add<0x118>(cx); cy = dpp_add<0x118>(cy);
                // row sums at lanes 15/31/47/63 -> 4 partials per wave
                if ((lane & 15) == 15)
                    partv[sc & 1][s][wid * 4 + (lane >> 4)] = make_float2(cx, cy);
            }
        } else if (is_prod) {
            // ---- producer: stage next chunk (same-iteration load/commit,
            //      4 barriers before first read); dots for sub-chunk sc+1 ----
            float4 pr0, pr1;
            const bool stage = (cpos == 0 && c + 1 < NCH);
            if (stage) {
                const float4* g = (const float4*)(xb + (size_t)(c + 1) * CH * DD);
                if (2 * ptid     < XF4) pr0 = g[2 * ptid];
                if (2 * ptid + 1 < XF4) pr1 = g[2 * ptid + 1];
            }

            if (sc + 1 < NSC) produce(sc + 1);

            if (stage) {
                if (2 * ptid     < XF4) xls[(c + 1) & 1][2 * ptid]     = pr0;
                if (2 * ptid + 1 < XF4) xls[(c + 1) & 1][2 * ptid + 1] = pr1;
            }
        } else {
            // ---- wave 8: layer-2 for the previous sub-chunk ----
            if (sc > 0) l2_chunk(sc - 1);
        }

        block_sync_lds();
    }

    // epilogue: layer-2 for the final sub-chunk (wave 8)
    if (wid == 8) {
        l2_chunk(NSC - 1);
        if (tid == 512 && st_l2) {
            outp[b * OO + 0] = (float)accx / 1000.0f;
            outp[b * OO + 1] = (float)accy / 1000.0f;
        }
    }
}

extern "C" void kernel_launch(void* const* d_in, const int* in_sizes, int n_in,
                              void* d_out, int out_size, void* d_ws, size_t ws_size,
                              hipStream_t stream) {
    const float* x  = (const float*)d_in[0];   // [256,1000,32]
    const float* w1 = (const float*)d_in[1];   // [32,200]
    const float* w2 = (const float*)d_in[2];   // [200,2]
    float* out = (float*)d_out;

    dim3 grid(2 * TB), block(576);
    hipLaunchKernelGGL(snn_fwd, grid, block, 0, stream, x, w1, w2, out);
}

// Round 21
// 311.034 us; speedup vs baseline: 1.1768x; 1.1750x over previous
//
#include <hip/hip_runtime.h>

// TwoLayerSNN forward: B=256, T=1000, D=32, H=200, O=2
// Round 21 = round 19 (2 redundant blocks/batch, halved stores) with the
// block reshaped to EXACTLY 8 waves (512 threads): the dedicated layer-2
// wave is folded onto producer wave 7 (produce -> stage-commit -> l2, all
// pre-barrier; partv parity unchanged). Hypothesis: 9-wave workgroups never
// co-schedule 2/CU (r17 VGPR, r18 VGPR-64bucket, r19 LDS<64KB all failed);
// 2 x 8 waves = 16 waves/CU may fit the packing rule. Math bit-identical.

constexpr int TB = 256;
constexpr int TT = 1000;
constexpr int DD = 32;
constexpr int HH = 200;
constexpr int OO = 2;
constexpr int CH = 40;                    // timesteps per x staging chunk (5 KB)
constexpr int NCH = TT / CH;              // 25
constexpr int SC = 8;                     // timesteps per barrier interval
constexpr int NSC = TT / SC;              // 125
constexpr int XF4 = CH * DD / 4;          // 320 float4 per chunk

typedef float v2f __attribute__((ext_vector_type(2)));

__device__ __forceinline__ v2f pk_fma(v2f a, v2f b, v2f c) {
#if __has_builtin(__builtin_elementwise_fma)
    return __builtin_elementwise_fma(a, b, c);
#else
    v2f r; r.x = fmaf(a.x, b.x, c.x); r.y = fmaf(a.y, b.y, c.y); return r;
#endif
}

template <int CTRL>
__device__ __forceinline__ float dpp_add(float v) {
    int t = __builtin_amdgcn_update_dpp(0, __float_as_int(v), CTRL, 0xf, 0xf, true);
    return v + __int_as_float(t);
}

__device__ __forceinline__ float read_lane_f(float v, int l) {
    return __int_as_float(__builtin_amdgcn_readlane(__float_as_int(v), l));
}

__device__ __forceinline__ void block_sync_lds() {
    // Order LDS only (validated r8-r20): drain lgkm, raw barrier.
    asm volatile("s_waitcnt lgkmcnt(0)" ::: "memory");
    __builtin_amdgcn_s_barrier();
    asm volatile("" ::: "memory");
}

__global__ __launch_bounds__(512, 4)
void snn_fwd(const float* __restrict__ x,
             const float* __restrict__ w1,
             const float* __restrict__ w2,
             float* __restrict__ out)
{
    const int b    = blockIdx.x >> 1;
    const int half = blockIdx.x & 1;           // which h-half this block STORES
    const int tid  = threadIdx.x;
    const int lane = tid & 63;
    const int wid  = tid >> 6;
    const bool is_cons = (wid < 4);             // waves 0-3: consumers
    const bool is_l2w  = (wid == 7);            // wave 7 also runs layer-2
    const int ptid = tid - 256;                 // producer-local 0..255
    const bool act = is_cons && (tid < HH);
    // store predicate: this block stores h in [half*100, half*100+100)
    const bool act_st = act && (tid >= half * 100) && (tid < half * 100 + 100);
    const bool st_l2  = (half == 0);

    float* __restrict__ outp = out;                        // [TB][OO]
    float* __restrict__ s1o  = out + (size_t)TB * OO;      // [TB][TT][HH]
    float* __restrict__ m1o  = s1o + (size_t)TB * TT * HH; // [TB][TT][HH]
    float* __restrict__ s2o  = m1o + (size_t)TB * TT * HH; // [TB][TT][OO]
    float* __restrict__ m2o  = s2o + (size_t)TB * TT * OO; // [TB][TT][OO]

    const float A_SYN1 = (float)0.8187307530779818;
    const float IN_SC1 = (float)((1.0 - 0.8187307530779818) * 5.0);
    const float A_MEM1 = (float)0.9048374180359595;
    const float B_MEM1 = (float)(1.0 - 0.9048374180359595);
    const float TH1    = 0.5f;
    const float A_SYN2 = (float)0.9048374180359595;
    const float IN_SC2 = (float)((1.0 - 0.9048374180359595) * 10.0);
    const float A_MEM2 = (float)0.9512294245007140;
    const float B_MEM2 = (float)(1.0 - 0.9512294245007140);
    const float TH2    = 1.0f;

    __shared__ float4 xls[2][XF4];                    // 2 x 5 KB
    __shared__ float  dotb[2][SC][HH];                // 2 x 6.4 KB
    __shared__ __align__(16) float2 partv[2][SC][16]; // 2 x 1 KB

    const float* __restrict__ xb = x + (size_t)b * TT * DD;

    // producer: 50 hidden units per wave; w1 column as 16 float2 pairs
    const int ph   = (wid - 4) * 50 + lane;          // producer h
    const bool pact = (wid >= 4) && (lane < 50);
    v2f w1e[DD / 4], w1o[DD / 4];
#pragma unroll
    for (int i = 0; i < DD / 4; ++i) {
        w1e[i] = pact ? v2f{w1[(4 * i) * HH + ph],     w1[(4 * i + 1) * HH + ph]} : v2f{0.f, 0.f};
        w1o[i] = pact ? v2f{w1[(4 * i + 2) * HH + ph], w1[(4 * i + 3) * HH + ph]} : v2f{0.f, 0.f};
    }
    // consumer: w2 row
    const float w2x = act ? w2[tid * OO + 0] : 0.0f;
    const float w2y = act ? w2[tid * OO + 1] : 0.0f;

    // stage chunk 0 (5 KB, 320 float4) using consumer threads (one-time)
    if (is_cons) {
        const float4* g = (const float4*)xb;
        if (2 * tid     < XF4) xls[0][2 * tid]     = g[2 * tid];
        if (2 * tid + 1 < XF4) xls[0][2 * tid + 1] = g[2 * tid + 1];
    }
    block_sync_lds();

    // produce(j): dots for sub-chunk j into dotb[j&1]. Same fma order as
    // r14-r19 (bit-identical); x processed in two 4-float4 groups.
    auto produce = [&](int j) {
        const int tj = j * SC;
        const float4* xq = &xls[(tj / CH) & 1][(tj % CH) * (DD / 4)];
#pragma unroll
        for (int s = 0; s < SC; ++s) {
            v2f A01 = {0.f, 0.f}, A23 = {0.f, 0.f};
            {
                const float4 X0 = xq[s * 8 + 0], X1 = xq[s * 8 + 1];
                const float4 X2 = xq[s * 8 + 2], X3 = xq[s * 8 + 3];
                A01 = pk_fma(v2f{X0.x, X0.y}, w1e[0], A01);
                A23 = pk_fma(v2f{X0.z, X0.w}, w1o[0], A23);
                A01 = pk_fma(v2f{X1.x, X1.y}, w1e[1], A01);
                A23 = pk_fma(v2f{X1.z, X1.w}, w1o[1], A23);
                A01 = pk_fma(v2f{X2.x, X2.y}, w1e[2], A01);
                A23 = pk_fma(v2f{X2.z, X2.w}, w1o[2], A23);
                A01 = pk_fma(v2f{X3.x, X3.y}, w1e[3], A01);
                A23 = pk_fma(v2f{X3.z, X3.w}, w1o[3], A23);
            }
            {
                const float4 X4 = xq[s * 8 + 4], X5 = xq[s * 8 + 5];
                const float4 X6 = xq[s * 8 + 6], X7 = xq[s * 8 + 7];
                A01 = pk_fma(v2f{X4.x, X4.y}, w1e[4], A01);
                A23 = pk_fma(v2f{X4.z, X4.w}, w1o[4], A23);
                A01 = pk_fma(v2f{X5.x, X5.y}, w1e[5], A01);
                A23 = pk_fma(v2f{X5.z, X5.w}, w1o[5], A23);
                A01 = pk_fma(v2f{X6.x, X6.y}, w1e[6], A01);
                A23 = pk_fma(v2f{X6.z, X6.w}, w1o[6], A23);
                A01 = pk_fma(v2f{X7.x, X7.y}, w1e[7], A01);
                A23 = pk_fma(v2f{X7.z, X7.w}, w1o[7], A23);
            }
            const float dotv = __fadd_rn(__fadd_rn(A01.x, A01.y),
                                         __fadd_rn(A23.x, A23.y));
            if (pact) dotb[j & 1][s][ph] = dotv;
        }
    };

    // prologue: fill dotb[0] for sub-chunk 0
    if (wid >= 4) produce(0);
    block_sync_lds();

    float syn1 = 0.0f, mem1 = 0.0f;
    double accx = 0.0, accy = 0.0;
    v2f syn2 = {0.f, 0.f}, mem2 = {0.f, 0.f};
    const v2f A2v  = {A_SYN2, A_SYN2};
    const v2f SC2v = {IN_SC2, IN_SC2};
    const v2f AM2v = {A_MEM2, A_MEM2};
    const v2f BM2v = {B_MEM2, B_MEM2};
    const v2f TH2v = {TH2, TH2};

    float* __restrict__ s1p = s1o + (size_t)b * TT * HH + tid;
    float* __restrict__ m1p = m1o + (size_t)b * TT * HH + tid;
    float2* __restrict__ s2p = (float2*)(s2o + (size_t)b * TT * OO);
    float2* __restrict__ m2p = (float2*)(m2o + (size_t)b * TT * OO);

    // layer-2 for sub-chunk j (wave 7): lane-parallel merge of the 16
    // row-partials (4 steps per pass, 2 passes), then the pk-packed serial
    // chain (per-component roundings identical to scalar __f*_rn; r14-r19).
    auto l2_chunk = [&](int j) {
#pragma clang fp contract(off)
        const int g = lane >> 4;     // step within pass (0..3)
        const int p = lane & 15;     // partial index
#pragma unroll
        for (int hf = 0; hf < SC / 4; ++hf) {
            const float2 v = partv[j & 1][4 * hf + g][p];
            float cxv = v.x, cyv = v.y;
            cxv = dpp_add<0x111>(cxv); cyv = dpp_add<0x111>(cyv);
            cxv = dpp_add<0x112>(cxv); cyv = dpp_add<0x112>(cyv);
            cxv = dpp_add<0x114>(cxv); cyv = dpp_add<0x114>(cyv);
            cxv = dpp_add<0x118>(cxv); cyv = dpp_add<0x118>(cyv);
            // merged sums at lanes 15/31/47/63 for steps 4*hf+0..3
#pragma unroll
            for (int gg = 0; gg < 4; ++gg) {
                const v2f d = {read_lane_f(cxv, 16 * gg + 15),
                               read_lane_f(cyv, 16 * gg + 15)};
                syn2 = (A2v * syn2) + (SC2v * d);
                mem2 = (AM2v * mem2) + (BM2v * syn2);
                const float s2x = (mem2.x - TH2 > 0.0f) ? 1.0f : 0.0f;
                const float s2y = (mem2.y - TH2 > 0.0f) ? 1.0f : 0.0f;
                const v2f s2v = {s2x, s2y};
                mem2 = mem2 - (s2v * TH2v);
                const int t = j * SC + 4 * hf + gg;
                if (tid == 448 && st_l2) {
                    s2p[t] = make_float2(s2x, s2y);
                    m2p[t] = make_float2(mem2.x, mem2.y);
                }
                if (t > 0) { accx += (double)mem2.x; accy += (double)mem2.y; }
            }
        }
    };

    for (int sc = 0; sc < NSC; ++sc) {
        const int t0   = sc * SC;
        const int c    = t0 / CH;
        const int cpos = t0 % CH;

        if (is_cons) {
            // ---- consumer: this sub-chunk's dots from LDS ----
            float D[SC];
#pragma unroll
            for (int s = 0; s < SC; ++s) D[s] = dotb[sc & 1][s][tid];

            // ---- 8 steps: recurrence + (half) stores + 4-level DPP ----
#pragma unroll
            for (int s = 0; s < SC; ++s) {
                const float dot = D[s];
                syn1 = __fadd_rn(__fmul_rn(A_SYN1, syn1), __fmul_rn(IN_SC1, dot));
                mem1 = __fadd_rn(__fmul_rn(A_MEM1, mem1), __fmul_rn(B_MEM1, syn1));
                const float s1v = (mem1 - TH1 > 0.0f) ? 1.0f : 0.0f;
                mem1 = __fsub_rn(mem1, __fmul_rn(s1v, TH1));

                if (act_st) {
                    s1p[(size_t)(t0 + s) * HH] = s1v;
                    m1p[(size_t)(t0 + s) * HH] = mem1;
                }

                float cx = s1v * w2x;
                float cy = s1v * w2y;
                cx = dpp_add<0x111>(cx); cy = dpp_add<0x111>(cy);
                cx = dpp_add<0x112>(cx); cy = dpp_add<0x112>(cy);
                cx = dpp_add<0x114>(cx); cy = dpp_add<0x114>(cy);
                cx = dpp_add<0x118>(cx); cy = dpp_add<0x118>(cy);
                // row sums at lanes 15/31/47/63 -> 4 partials per wave
                if ((lane & 15) == 15)
                    partv[sc & 1][s][wid * 4 + (lane >> 4)] = make_float2(cx, cy);
            }
        } else {
            // ---- producers (waves 4-7): stage next chunk (same-iteration
            //      load/commit); dots for sub-chunk sc+1 ----
            float4 pr0, pr1;
            const bool stage = (cpos == 0 && c + 1 < NCH);
            if (stage) {
                const float4* g = (const float4*)(xb + (size_t)(c + 1) * CH * DD);
                if (2 * ptid     < XF4) pr0 = g[2 * ptid];
                if (2 * ptid + 1 < XF4) pr1 = g[2 * ptid + 1];
            }

            if (sc + 1 < NSC) produce(sc + 1);

            if (stage) {
                if (2 * ptid     < XF4) xls[(c + 1) & 1][2 * ptid]     = pr0;
                if (2 * ptid + 1 < XF4) xls[(c + 1) & 1][2 * ptid + 1] = pr1;
            }

            // ---- wave 7 additionally: layer-2 for the previous sub-chunk
            //      (reads partv[(sc-1)&1], written before the last barrier;
            //      consumers are writing partv[sc&1] -> disjoint buffer) ----
            if (is_l2w && sc > 0) l2_chunk(sc - 1);
        }

        block_sync_lds();
    }

    // epilogue: layer-2 for the final sub-chunk (wave 7)
    if (is_l2w) {
        l2_chunk(NSC - 1);
        if (tid == 448 && st_l2) {
            outp[b * OO + 0] = (float)accx / 1000.0f;
            outp[b * OO + 1] = (float)accy / 1000.0f;
        }
    }
}

extern "C" void kernel_launch(void* const* d_in, const int* in_sizes, int n_in,
                              void* d_out, int out_size, void* d_ws, size_t ws_size,
                              hipStream_t stream) {
    const float* x  = (const float*)d_in[0];   // [256,1000,32]
    const float* w1 = (const float*)d_in[1];   // [32,200]
    const float* w2 = (const float*)d_in[2];   // [200,2]
    float* out = (float*)d_out;

    dim3 grid(2 * TB), block(512);
    hipLaunchKernelGGL(snn_fwd, grid, block, 0, stream, x, w1, w2, out);
}

// Round 22
// 207.206 us; speedup vs baseline: 1.7665x; 1.5011x over previous
//
#include <hip/hip_runtime.h>

// TwoLayerSNN forward: B=256, T=1000, D=32, H=200, O=2
// Round 22 = r15 structure (182us) with the producer x-broadcast redundancy
// removed. Key fact (m134): ds_read_b128 ~12cy issue on the shared LDS pipe;
// r15's 4 producer waves re-read the same x = 32 b128/step ~ 384cy/step of
// pipe time = the measured 440cy/step plateau. Fix: d-split producers into
// 2 waves. Wave A computes pA=(a0+a1) over pairs (x[4i],x[4i+1])*w1e for all
// 200 h (4 h/lane); wave B computes pB=(a2+a3) over (x[4i+2],x[4i+3])*w1o.
// Consumer: D = fadd(pA,pB) == r15's (A01.x+A01.y)+(A23.x+A23.y) ->
// BIT-IDENTICAL. x staged in A/B-split LDS layouts (same staging instrs);
// producer x reads drop 32 -> 8 b128/step; dotb writes become b128.
// Block = 7 waves: 4 consumers (also stage x), prodA, prodB, l2 wave.
// Recurrence / DPP / partv / pk-l2 are r15 text verbatim.

constexpr int TB = 256;
constexpr int TT = 1000;
constexpr int DD = 32;
constexpr int HH = 200;
constexpr int OO = 2;
constexpr int CH = 40;                    // timesteps per x staging chunk
constexpr int NCH = TT / CH;              // 25
constexpr int SC = 8;                     // timesteps per barrier interval
constexpr int NSC = TT / SC;              // 125
constexpr int XF4 = CH * DD / 4;          // 320 float4 per chunk
constexpr int HP = 256;                   // padded H for dotp (OOB-safe reads)

typedef float v2f __attribute__((ext_vector_type(2)));

__device__ __forceinline__ v2f pk_fma(v2f a, v2f b, v2f c) {
#if __has_builtin(__builtin_elementwise_fma)
    return __builtin_elementwise_fma(a, b, c);
#else
    v2f r; r.x = fmaf(a.x, b.x, c.x); r.y = fmaf(a.y, b.y, c.y); return r;
#endif
}

template <int CTRL>
__device__ __forceinline__ float dpp_add(float v) {
    int t = __builtin_amdgcn_update_dpp(0, __float_as_int(v), CTRL, 0xf, 0xf, true);
    return v + __int_as_float(t);
}

__device__ __forceinline__ float read_lane_f(float v, int l) {
    return __int_as_float(__builtin_amdgcn_readlane(__float_as_int(v), l));
}

__device__ __forceinline__ void block_sync_lds() {
    // Order LDS only (validated r8-r21): drain lgkm, raw barrier.
    asm volatile("s_waitcnt lgkmcnt(0)" ::: "memory");
    __builtin_amdgcn_s_barrier();
    asm volatile("" ::: "memory");
}

__global__ __launch_bounds__(448, 1)
void snn_fwd(const float* __restrict__ x,
             const float* __restrict__ w1,
             const float* __restrict__ w2,
             float* __restrict__ out)
{
    const int b    = blockIdx.x;
    const int tid  = threadIdx.x;
    const int lane = tid & 63;
    const int wid  = tid >> 6;
    const bool is_cons  = (wid < 4);
    const bool is_prodA = (wid == 4);
    const bool is_prodB = (wid == 5);
    const bool is_l2    = (wid == 6);
    const bool act = is_cons && (tid < HH);

    float* __restrict__ outp = out;                        // [TB][OO]
    float* __restrict__ s1o  = out + (size_t)TB * OO;      // [TB][TT][HH]
    float* __restrict__ m1o  = s1o + (size_t)TB * TT * HH; // [TB][TT][HH]
    float* __restrict__ s2o  = m1o + (size_t)TB * TT * HH; // [TB][TT][OO]
    float* __restrict__ m2o  = s2o + (size_t)TB * TT * OO; // [TB][TT][OO]

    const float A_SYN1 = (float)0.8187307530779818;
    const float IN_SC1 = (float)((1.0 - 0.8187307530779818) * 5.0);
    const float A_MEM1 = (float)0.9048374180359595;
    const float B_MEM1 = (float)(1.0 - 0.9048374180359595);
    const float TH1    = 0.5f;
    const float A_SYN2 = (float)0.9048374180359595;
    const float IN_SC2 = (float)((1.0 - 0.9048374180359595) * 10.0);
    const float A_MEM2 = (float)0.9512294245007140;
    const float B_MEM2 = (float)(1.0 - 0.9512294245007140);
    const float TH2    = 1.0f;

    __shared__ float4 xlsA[2][CH * 4];                 // pairs (x[4i],x[4i+1]) 5KB
    __shared__ float4 xlsB[2][CH * 4];                 // pairs (x[4i+2],x[4i+3]) 5KB
    __shared__ __align__(16) float dotp[2][2][SC][HP]; // part x parity x step x h, 32.8KB
    __shared__ __align__(16) float2 partv[2][SC][16];  // 2KB

    const float* __restrict__ xb = x + (size_t)b * TT * DD;

    // producer weights: 4 h per lane (lanes 0..49), d-half by wave
    const bool pact = (is_prodA || is_prodB) && (lane < 50);
    const int hb = lane * 4;
    v2f wreg[4][8];
#pragma unroll
    for (int j = 0; j < 4; ++j) {
#pragma unroll
        for (int i = 0; i < 8; ++i) {
            const int d0 = is_prodB ? (4 * i + 2) : (4 * i);
            wreg[j][i] = pact ? v2f{w1[d0 * HH + hb + j], w1[(d0 + 1) * HH + hb + j]}
                              : v2f{0.f, 0.f};
        }
    }
    // consumer w2
    const float w2x = act ? w2[tid * OO + 0] : 0.0f;
    const float w2y = act ? w2[tid * OO + 1] : 0.0f;

    // stage chunk 0: consumer threads 0..159, scatter into A/B layouts
    if (is_cons && tid < 160) {
        const float4* g = (const float4*)xb;
        const float4 l0 = g[2 * tid];
        const float4 l1 = g[2 * tid + 1];
        const int st = tid >> 2, q = tid & 3;
        xlsA[0][st * 4 + q] = make_float4(l0.x, l0.y, l1.x, l1.y);
        xlsB[0][st * 4 + q] = make_float4(l0.z, l0.w, l1.z, l1.w);
    }
    block_sync_lds();

    // produce(j): this wave's partial dots for sub-chunk j into dotp[part][j&1].
    // fma order per h identical to r15's A01 (wave A) / A23 (wave B) chains.
    auto produce = [&](int j) {
        const int tj  = j * SC;
        const int buf = (tj / CH) & 1, base = (tj % CH) * 4;
        const float4* xq = is_prodA ? &xlsA[buf][base] : &xlsB[buf][base];
        float* dp = &dotp[is_prodA ? 0 : 1][j & 1][0][0];
#pragma unroll
        for (int s = 0; s < SC; ++s) {
            const float4 P0 = xq[s * 4 + 0], P1 = xq[s * 4 + 1];
            const float4 P2 = xq[s * 4 + 2], P3 = xq[s * 4 + 3];
            v2f acc[4] = {{0.f, 0.f}, {0.f, 0.f}, {0.f, 0.f}, {0.f, 0.f}};
#pragma unroll
            for (int jj = 0; jj < 4; ++jj) {
                acc[jj] = pk_fma(v2f{P0.x, P0.y}, wreg[jj][0], acc[jj]);
                acc[jj] = pk_fma(v2f{P0.z, P0.w}, wreg[jj][1], acc[jj]);
                acc[jj] = pk_fma(v2f{P1.x, P1.y}, wreg[jj][2], acc[jj]);
                acc[jj] = pk_fma(v2f{P1.z, P1.w}, wreg[jj][3], acc[jj]);
                acc[jj] = pk_fma(v2f{P2.x, P2.y}, wreg[jj][4], acc[jj]);
                acc[jj] = pk_fma(v2f{P2.z, P2.w}, wreg[jj][5], acc[jj]);
                acc[jj] = pk_fma(v2f{P3.x, P3.y}, wreg[jj][6], acc[jj]);
                acc[jj] = pk_fma(v2f{P3.z, P3.w}, wreg[jj][7], acc[jj]);
            }
            if (pact) {
                const float4 dv = make_float4(
                    __fadd_rn(acc[0].x, acc[0].y), __fadd_rn(acc[1].x, acc[1].y),
                    __fadd_rn(acc[2].x, acc[2].y), __fadd_rn(acc[3].x, acc[3].y));
                *(float4*)&dp[s * HP + hb] = dv;   // h = 4*lane .. 4*lane+3
            }
        }
    };

    if (is_prodA || is_prodB) produce(0);
    block_sync_lds();

    float syn1 = 0.0f, mem1 = 0.0f;
    double accx = 0.0, accy = 0.0;
    v2f syn2 = {0.f, 0.f}, mem2 = {0.f, 0.f};
    const v2f A2v  = {A_SYN2, A_SYN2};
    const v2f SC2v = {IN_SC2, IN_SC2};
    const v2f AM2v = {A_MEM2, A_MEM2};
    const v2f BM2v = {B_MEM2, B_MEM2};
    const v2f TH2v = {TH2, TH2};

    // persistent staging regs (consumers; r6 lifetime lesson)
    float4 pr0 = make_float4(0.f, 0.f, 0.f, 0.f);
    float4 pr1 = make_float4(0.f, 0.f, 0.f, 0.f);

    float* __restrict__ s1p = s1o + (size_t)b * TT * HH + tid;
    float* __restrict__ m1p = m1o + (size_t)b * TT * HH + tid;
    float2* __restrict__ s2p = (float2*)(s2o + (size_t)b * TT * OO);
    float2* __restrict__ m2p = (float2*)(m2o + (size_t)b * TT * OO);

    // layer-2 for sub-chunk j (wave 6): r15 text, store lane tid==384
    auto l2_chunk = [&](int j) {
#pragma clang fp contract(off)
        const int g = lane >> 4;
        const int p = lane & 15;
#pragma unroll
        for (int hf = 0; hf < SC / 4; ++hf) {
            const float2 v = partv[j & 1][4 * hf + g][p];
            float cxv = v.x, cyv = v.y;
            cxv = dpp_add<0x111>(cxv); cyv = dpp_add<0x111>(cyv);
            cxv = dpp_add<0x112>(cxv); cyv = dpp_add<0x112>(cyv);
            cxv = dpp_add<0x114>(cxv); cyv = dpp_add<0x114>(cyv);
            cxv = dpp_add<0x118>(cxv); cyv = dpp_add<0x118>(cyv);
#pragma unroll
            for (int gg = 0; gg < 4; ++gg) {
                const v2f d = {read_lane_f(cxv, 16 * gg + 15),
                               read_lane_f(cyv, 16 * gg + 15)};
                syn2 = (A2v * syn2) + (SC2v * d);
                mem2 = (AM2v * mem2) + (BM2v * syn2);
                const float s2x = (mem2.x - TH2 > 0.0f) ? 1.0f : 0.0f;
                const float s2y = (mem2.y - TH2 > 0.0f) ? 1.0f : 0.0f;
                const v2f s2v = {s2x, s2y};
                mem2 = mem2 - (s2v * TH2v);
                const int t = j * SC + 4 * hf + gg;
                if (tid == 384) {
                    s2p[t] = make_float2(s2x, s2y);
                    m2p[t] = make_float2(mem2.x, mem2.y);
                }
                if (t > 0) { accx += (double)mem2.x; accy += (double)mem2.y; }
            }
        }
    };

    for (int sc = 0; sc < NSC; ++sc) {
        const int t0 = sc * SC;
        const int c  = sc / 5;          // chunk index (5 sub-chunks per chunk)

        if (is_cons) {
            // staging loads for chunk c+1 (issued 3 barriers before commit)
            if ((sc % 5) == 0 && c + 1 < NCH && tid < 160) {
                const float4* g = (const float4*)(xb + (size_t)(c + 1) * CH * DD);
                pr0 = g[2 * tid];
                pr1 = g[2 * tid + 1];
            }

            // D = pA + pB  (bit-identical to r15's 4-acc merge)
            float D[SC];
#pragma unroll
            for (int s = 0; s < SC; ++s)
                D[s] = __fadd_rn(dotp[0][sc & 1][s][tid], dotp[1][sc & 1][s][tid]);

            // 8 steps: recurrence + stores + 4-level DPP (r15 text)
#pragma unroll
            for (int s = 0; s < SC; ++s) {
                const float dot = D[s];
                syn1 = __fadd_rn(__fmul_rn(A_SYN1, syn1), __fmul_rn(IN_SC1, dot));
                mem1 = __fadd_rn(__fmul_rn(A_MEM1, mem1), __fmul_rn(B_MEM1, syn1));
                const float s1v = (mem1 - TH1 > 0.0f) ? 1.0f : 0.0f;
                mem1 = __fsub_rn(mem1, __fmul_rn(s1v, TH1));

                if (act) {
                    s1p[(size_t)(t0 + s) * HH] = s1v;
                    m1p[(size_t)(t0 + s) * HH] = mem1;
                }

                float cx = s1v * w2x;
                float cy = s1v * w2y;
                cx = dpp_add<0x111>(cx); cy = dpp_add<0x111>(cy);
                cx = dpp_add<0x112>(cx); cy = dpp_add<0x112>(cy);
                cx = dpp_add<0x114>(cx); cy = dpp_add<0x114>(cy);
                cx = dpp_add<0x118>(cx); cy = dpp_add<0x118>(cy);
                if ((lane & 15) == 15)
                    partv[sc & 1][s][wid * 4 + (lane >> 4)] = make_float2(cx, cy);
            }

            // commit chunk c+1 (one barrier before producers first read it)
            if ((sc % 5) == 3 && c + 1 < NCH && tid < 160) {
                const int st = tid >> 2, q = tid & 3, bufn = (c + 1) & 1;
                xlsA[bufn][st * 4 + q] = make_float4(pr0.x, pr0.y, pr1.x, pr1.y);
                xlsB[bufn][st * 4 + q] = make_float4(pr0.z, pr0.w, pr1.z, pr1.w);
            }
        } else if (is_prodA || is_prodB) {
            if (sc + 1 < NSC) produce(sc + 1);
        } else {
            if (sc > 0) l2_chunk(sc - 1);
        }

        block_sync_lds();
    }

    // epilogue: layer-2 for the final sub-chunk (wave 6)
    if (is_l2) {
        l2_chunk(NSC - 1);
        if (tid == 384) {
            outp[b * OO + 0] = (float)accx / 1000.0f;
            outp[b * OO + 1] = (float)accy / 1000.0f;
        }
    }
}

extern "C" void kernel_launch(void* const* d_in, const int* in_sizes, int n_in,
                              void* d_out, int out_size, void* d_ws, size_t ws_size,
                              hipStream_t stream) {
    const float* x  = (const float*)d_in[0];   // [256,1000,32]
    const float* w1 = (const float*)d_in[1];   // [32,200]
    const float* w2 = (const float*)d_in[2];   // [200,2]
    float* out = (float*)d_out;

    dim3 grid(TB), block(448);
    hipLaunchKernelGGL(snn_fwd, grid, block, 0, stream, x, w1, w2, out);
}